// Round 3
// baseline (309.869 us; speedup 1.0000x reference)
//
#include <hip/hip_runtime.h>

#define T_TOK 8192
#define D_DIM 128
#define N_NEU 4096

// ---------------------------------------------------------------------------
// Kernel 1: blocks 0..15  -> acts (last 16 tokens) + window means w=1,2,4,8,16
//           block 16      -> qkv -> 32x32 attention -> mean -> LayerNorm -> yvec
// ---------------------------------------------------------------------------
struct SmemAttn {
    float xs[32][128];   // last-32 tokens; later overwritten with v
    float qs[32][128];
    float kt[128][33];   // k transposed, padded (bank-conflict-free)
    float ps[32][33];
    float pbar[32];
    float mvec[128];
    float red[2];
};
union Smem1 {
    float xs16[16][128];
    SmemAttn attn;
};

__global__ void means_attn_kernel(
    const float* __restrict__ x,
    const float* __restrict__ neuronW, const float* __restrict__ neuronB,
    const float* __restrict__ Wq, const float* __restrict__ bq,
    const float* __restrict__ Wk, const float* __restrict__ bk,
    const float* __restrict__ Wv, const float* __restrict__ bv,
    const float* __restrict__ ln_g, const float* __restrict__ ln_b,
    float* __restrict__ means,   // [5][4096]
    float* __restrict__ yvec)    // [128]
{
    __shared__ Smem1 sm;
    const int tid = threadIdx.x;
    const int bid = blockIdx.x;

    if (bid < 16) {
        int n = bid * 256 + tid;
        for (int idx = tid; idx < 16 * 128; idx += 256) {
            int t = idx >> 7, d = idx & 127;
            sm.xs16[t][d] = x[(size_t)(T_TOK - 16 + t) * D_DIM + d];
        }
        __syncthreads();
        float acc[16];
        float bias = neuronB[n];
#pragma unroll
        for (int t = 0; t < 16; ++t) acc[t] = bias;
        for (int d = 0; d < 128; ++d) {
            float w = neuronW[(size_t)d * N_NEU + n];
#pragma unroll
            for (int t = 0; t < 16; ++t) acc[t] += sm.xs16[t][d] * w;
        }
#pragma unroll
        for (int t = 0; t < 16; ++t) acc[t] = tanhf(acc[t]);  // |tanh|<=1 => clip no-op
        float s1 = acc[15];
        float s2 = s1 + acc[14];
        float s4 = s2 + acc[13] + acc[12];
        float s8 = s4 + acc[11] + acc[10] + acc[9] + acc[8];
        float s16 = s8 + acc[7] + acc[6] + acc[5] + acc[4] + acc[3] + acc[2] + acc[1] + acc[0];
        means[0 * N_NEU + n] = s1;
        means[1 * N_NEU + n] = s2 * 0.5f;
        means[2 * N_NEU + n] = s4 * 0.25f;
        means[3 * N_NEU + n] = s8 * 0.125f;
        means[4 * N_NEU + n] = s16 * 0.0625f;
        return;
    }

    // ---- block 16: attention chain entirely in LDS ----
    for (int idx = tid; idx < 32 * 128; idx += 256) {
        int t = idx >> 7, d = idx & 127;
        sm.attn.xs[t][d] = x[(size_t)(T_TOK - 32 + t) * D_DIM + d];
    }
    __syncthreads();

    const int d = tid & 127;
    const int g = tid >> 7;   // row group {0,1}: rows g*16 .. g*16+15
    float vacc[16];
    {
        // q -> qs
        float acc[16];
        float bias = bq[d];
#pragma unroll
        for (int i = 0; i < 16; ++i) acc[i] = bias;
        for (int e = 0; e < 128; ++e) {
            float w = Wq[e * 128 + d];
#pragma unroll
            for (int i = 0; i < 16; ++i) acc[i] += sm.attn.xs[g * 16 + i][e] * w;
        }
#pragma unroll
        for (int i = 0; i < 16; ++i) sm.attn.qs[g * 16 + i][d] = acc[i];
        // k -> kt (transposed)
        bias = bk[d];
#pragma unroll
        for (int i = 0; i < 16; ++i) acc[i] = bias;
        for (int e = 0; e < 128; ++e) {
            float w = Wk[e * 128 + d];
#pragma unroll
            for (int i = 0; i < 16; ++i) acc[i] += sm.attn.xs[g * 16 + i][e] * w;
        }
#pragma unroll
        for (int i = 0; i < 16; ++i) sm.attn.kt[d][g * 16 + i] = acc[i];
        // v -> registers (xs still needed)
        bias = bv[d];
#pragma unroll
        for (int i = 0; i < 16; ++i) vacc[i] = bias;
        for (int e = 0; e < 128; ++e) {
            float w = Wv[e * 128 + d];
#pragma unroll
            for (int i = 0; i < 16; ++i) vacc[i] += sm.attn.xs[g * 16 + i][e] * w;
        }
    }
    __syncthreads();
    // overwrite xs with v
#pragma unroll
    for (int i = 0; i < 16; ++i) sm.attn.xs[g * 16 + i][d] = vacc[i];
    __syncthreads();

    const float scale = 0.08838834764831845f;  // 1/sqrt(128)
#pragma unroll
    for (int rep = 0; rep < 4; ++rep) {
        int idx = tid + rep * 256;
        int i = idx >> 5, j = idx & 31;
        float acc = 0.f;
        for (int e = 0; e < 128; ++e) acc += sm.attn.qs[i][e] * sm.attn.kt[e][j];
        sm.attn.ps[i][j] = acc * scale;
    }
    __syncthreads();
    if (tid < 32) {    // softmax over row tid
        float mx = -1e30f;
        for (int j = 0; j < 32; ++j) mx = fmaxf(mx, sm.attn.ps[tid][j]);
        float s = 0.f;
        for (int j = 0; j < 32; ++j) { float e = expf(sm.attn.ps[tid][j] - mx); sm.attn.ps[tid][j] = e; s += e; }
        float inv = 1.f / s;
        for (int j = 0; j < 32; ++j) sm.attn.ps[tid][j] *= inv;
    }
    __syncthreads();
    if (tid < 32) {    // mean over queries of column tid
        float s = 0.f;
        for (int i = 0; i < 32; ++i) s += sm.attn.ps[i][tid];
        sm.attn.pbar[tid] = s * (1.f / 32.f);
    }
    __syncthreads();
    if (tid < 128) {   // attended mean[d] = sum_j pbar[j] * v[j][d]
        float s = 0.f;
        for (int j = 0; j < 32; ++j) s += sm.attn.pbar[j] * sm.attn.xs[j][tid];
        sm.attn.mvec[tid] = s;
    }
    __syncthreads();
    if (tid < 64) {    // mean (wave 0 shuffle reduce)
        float p = sm.attn.mvec[tid] + sm.attn.mvec[tid + 64];
        for (int off = 32; off; off >>= 1) p += __shfl_down(p, off);
        if (tid == 0) sm.attn.red[0] = p * (1.f / 128.f);
    }
    __syncthreads();
    float mu = sm.attn.red[0];
    if (tid < 64) {    // variance
        float t1 = sm.attn.mvec[tid] - mu, t2 = sm.attn.mvec[tid + 64] - mu;
        float p = t1 * t1 + t2 * t2;
        for (int off = 32; off; off >>= 1) p += __shfl_down(p, off);
        if (tid == 0) sm.attn.red[1] = rsqrtf(p * (1.f / 128.f) + 1e-5f);
    }
    __syncthreads();
    if (tid < 128) {
        yvec[tid] = (sm.attn.mvec[tid] - mu) * sm.attn.red[1] * ln_g[tid] + ln_b[tid];
    }
}

// ---------------------------------------------------------------------------
// Kernel 2: proj = LN(attn_mean) @ projW + projb, and build the full weighted
// vector v[24576] = concat_s( mean_s * norm_w[s] ).  16 blocks x 256.
// ---------------------------------------------------------------------------
__global__ void proj_build_v_kernel(const float* __restrict__ yvec,
                                    const float* __restrict__ projW,
                                    const float* __restrict__ projb,
                                    const float* __restrict__ ww,
                                    const float* __restrict__ means,  // [5][4096]
                                    float* __restrict__ v)            // [6][4096]
{
    __shared__ float ys[128];
    int tid = threadIdx.x;
    int n = blockIdx.x * 256 + tid;
    if (tid < 128) ys[tid] = yvec[tid];
    __syncthreads();
    float acc = projb[n];
    for (int d = 0; d < 128; ++d) acc += ys[d] * projW[(size_t)d * N_NEU + n];

    float denom = 0.1f;
#pragma unroll
    for (int i = 0; i < 6; ++i) denom += ww[i];
    float inv = 1.f / denom;
#pragma unroll
    for (int s = 0; s < 5; ++s)
        v[s * N_NEU + n] = means[s * N_NEU + n] * ((ww[s] + 0.1f) * inv);
    v[5 * N_NEU + n] = acc * ((ww[5] + 0.1f) * inv);
}

// ---------------------------------------------------------------------------
// Kernel 3: out = v[24576] @ comboW[24576][4096] + combob.
// 128 blocks x 1024 threads; block owns 32 cols (128 B/row/thread = full
// cache line), all rows. Shuffle + LDS reduce. Deterministic, no partials.
// ---------------------------------------------------------------------------
__global__ __launch_bounds__(1024, 4) void combo_kernel(
    const float* __restrict__ v,       // [24576]
    const float* __restrict__ comboW,  // [24576][4096]
    const float* __restrict__ combob,  // [4096]
    float* __restrict__ out)           // [4096]
{
    __shared__ float red[16][32];
    const int tid = threadIdx.x;            // 1024
    const int c0 = blockIdx.x * 32;         // 32 cols per block
    const float4* W4 = reinterpret_cast<const float4*>(comboW);

    float acc[32];
#pragma unroll
    for (int c = 0; c < 32; ++c) acc[c] = 0.f;

    for (int it = 0; it < 24; ++it) {
        int r = it * 1024 + tid;
        float vr = v[r];
        size_t base = (size_t)r * 1024 + (c0 >> 2);
#pragma unroll
        for (int u = 0; u < 8; ++u) {
            float4 w = W4[base + u];
            acc[u * 4 + 0] += vr * w.x;
            acc[u * 4 + 1] += vr * w.y;
            acc[u * 4 + 2] += vr * w.z;
            acc[u * 4 + 3] += vr * w.w;
        }
    }
    // wave reduce each acc over 64 lanes
#pragma unroll
    for (int c = 0; c < 32; ++c) {
        float a = acc[c];
        for (int off = 32; off; off >>= 1) a += __shfl_down(a, off);
        acc[c] = a;
    }
    int wave = tid >> 6;
    if ((tid & 63) == 0) {
#pragma unroll
        for (int c = 0; c < 32; ++c) red[wave][c] = acc[c];
    }
    __syncthreads();
    if (tid < 32) {
        float s = combob[c0 + tid];
#pragma unroll
        for (int w = 0; w < 16; ++w) s += red[w][tid];
        out[c0 + tid] = s;
    }
}

// ---------------------------------------------------------------------------
extern "C" void kernel_launch(void* const* d_in, const int* in_sizes, int n_in,
                              void* d_out, int out_size, void* d_ws, size_t ws_size,
                              hipStream_t stream) {
    const float* inputEmbeds = (const float*)d_in[0];
    const float* neuronW     = (const float*)d_in[1];
    const float* neuronB     = (const float*)d_in[2];
    const float* Wq          = (const float*)d_in[3];
    const float* bq          = (const float*)d_in[4];
    const float* Wk          = (const float*)d_in[5];
    const float* bk          = (const float*)d_in[6];
    const float* Wv          = (const float*)d_in[7];
    const float* bv          = (const float*)d_in[8];
    const float* ln_g        = (const float*)d_in[9];
    const float* ln_b        = (const float*)d_in[10];
    const float* projW       = (const float*)d_in[11];
    const float* projb       = (const float*)d_in[12];
    const float* ww          = (const float*)d_in[13];
    const float* comboW      = (const float*)d_in[14];
    const float* combob      = (const float*)d_in[15];
    float* out = (float*)d_out;
    float* ws  = (float*)d_ws;

    float* means = ws;            // 5*4096
    float* yvec  = ws + 20480;    // 128
    float* v     = ws + 20608;    // 6*4096

    means_attn_kernel<<<17, 256, 0, stream>>>(inputEmbeds, neuronW, neuronB,
                                              Wq, bq, Wk, bk, Wv, bv,
                                              ln_g, ln_b, means, yvec);
    proj_build_v_kernel<<<16, 256, 0, stream>>>(yvec, projW, projb, ww, means, v);
    combo_kernel<<<128, 1024, 0, stream>>>(v, comboW, combob, out);
}

// Round 4
// 155.558 us; speedup vs baseline: 1.9920x; 1.9920x over previous
//
#include <hip/hip_runtime.h>

#define T_TOK 8192
#define D_DIM 128
#define N_NEU 4096
#define RPC 128            // rows per chunk in combo phase
#define NCHUNK 192         // 24576 / RPC

// ---------------------------------------------------------------------------
// Kernel 1: blocks 0..15  -> acts (last 16 tokens) + window means w=1,2,4,8,16
//           block 16      -> qkv -> 32x32 attention -> mean -> LayerNorm -> yvec
// (verified in round 3: absmax 6.1e-05)
// ---------------------------------------------------------------------------
struct SmemAttn {
    float xs[32][128];   // last-32 tokens; later overwritten with v
    float qs[32][128];
    float kt[128][33];   // k transposed, padded (bank-conflict-free)
    float ps[32][33];
    float pbar[32];
    float mvec[128];
    float red[2];
};
union Smem1 {
    float xs16[16][128];
    SmemAttn attn;
};

__global__ void means_attn_kernel(
    const float* __restrict__ x,
    const float* __restrict__ neuronW, const float* __restrict__ neuronB,
    const float* __restrict__ Wq, const float* __restrict__ bq,
    const float* __restrict__ Wk, const float* __restrict__ bk,
    const float* __restrict__ Wv, const float* __restrict__ bv,
    const float* __restrict__ ln_g, const float* __restrict__ ln_b,
    float* __restrict__ means,   // [5][4096]
    float* __restrict__ yvec)    // [128]
{
    __shared__ Smem1 sm;
    const int tid = threadIdx.x;
    const int bid = blockIdx.x;

    if (bid < 16) {
        int n = bid * 256 + tid;
        for (int idx = tid; idx < 16 * 128; idx += 256) {
            int t = idx >> 7, d = idx & 127;
            sm.xs16[t][d] = x[(size_t)(T_TOK - 16 + t) * D_DIM + d];
        }
        __syncthreads();
        float acc[16];
        float bias = neuronB[n];
#pragma unroll
        for (int t = 0; t < 16; ++t) acc[t] = bias;
        for (int d = 0; d < 128; ++d) {
            float w = neuronW[(size_t)d * N_NEU + n];
#pragma unroll
            for (int t = 0; t < 16; ++t) acc[t] += sm.xs16[t][d] * w;
        }
#pragma unroll
        for (int t = 0; t < 16; ++t) acc[t] = tanhf(acc[t]);  // |tanh|<=1 => clip no-op
        float s1 = acc[15];
        float s2 = s1 + acc[14];
        float s4 = s2 + acc[13] + acc[12];
        float s8 = s4 + acc[11] + acc[10] + acc[9] + acc[8];
        float s16 = s8 + acc[7] + acc[6] + acc[5] + acc[4] + acc[3] + acc[2] + acc[1] + acc[0];
        means[0 * N_NEU + n] = s1;
        means[1 * N_NEU + n] = s2 * 0.5f;
        means[2 * N_NEU + n] = s4 * 0.25f;
        means[3 * N_NEU + n] = s8 * 0.125f;
        means[4 * N_NEU + n] = s16 * 0.0625f;
        return;
    }

    // ---- block 16: attention chain entirely in LDS ----
    for (int idx = tid; idx < 32 * 128; idx += 256) {
        int t = idx >> 7, d = idx & 127;
        sm.attn.xs[t][d] = x[(size_t)(T_TOK - 32 + t) * D_DIM + d];
    }
    __syncthreads();

    const int d = tid & 127;
    const int g = tid >> 7;   // row group {0,1}: rows g*16 .. g*16+15
    float vacc[16];
    {
        float acc[16];
        float bias = bq[d];
#pragma unroll
        for (int i = 0; i < 16; ++i) acc[i] = bias;
        for (int e = 0; e < 128; ++e) {
            float w = Wq[e * 128 + d];
#pragma unroll
            for (int i = 0; i < 16; ++i) acc[i] += sm.attn.xs[g * 16 + i][e] * w;
        }
#pragma unroll
        for (int i = 0; i < 16; ++i) sm.attn.qs[g * 16 + i][d] = acc[i];
        bias = bk[d];
#pragma unroll
        for (int i = 0; i < 16; ++i) acc[i] = bias;
        for (int e = 0; e < 128; ++e) {
            float w = Wk[e * 128 + d];
#pragma unroll
            for (int i = 0; i < 16; ++i) acc[i] += sm.attn.xs[g * 16 + i][e] * w;
        }
#pragma unroll
        for (int i = 0; i < 16; ++i) sm.attn.kt[d][g * 16 + i] = acc[i];
        bias = bv[d];
#pragma unroll
        for (int i = 0; i < 16; ++i) vacc[i] = bias;
        for (int e = 0; e < 128; ++e) {
            float w = Wv[e * 128 + d];
#pragma unroll
            for (int i = 0; i < 16; ++i) vacc[i] += sm.attn.xs[g * 16 + i][e] * w;
        }
    }
    __syncthreads();
#pragma unroll
    for (int i = 0; i < 16; ++i) sm.attn.xs[g * 16 + i][d] = vacc[i];  // xs := v
    __syncthreads();

    const float scale = 0.08838834764831845f;  // 1/sqrt(128)
#pragma unroll
    for (int rep = 0; rep < 4; ++rep) {
        int idx = tid + rep * 256;
        int i = idx >> 5, j = idx & 31;
        float acc = 0.f;
        for (int e = 0; e < 128; ++e) acc += sm.attn.qs[i][e] * sm.attn.kt[e][j];
        sm.attn.ps[i][j] = acc * scale;
    }
    __syncthreads();
    if (tid < 32) {    // softmax over row tid
        float mx = -1e30f;
        for (int j = 0; j < 32; ++j) mx = fmaxf(mx, sm.attn.ps[tid][j]);
        float s = 0.f;
        for (int j = 0; j < 32; ++j) { float e = expf(sm.attn.ps[tid][j] - mx); sm.attn.ps[tid][j] = e; s += e; }
        float inv = 1.f / s;
        for (int j = 0; j < 32; ++j) sm.attn.ps[tid][j] *= inv;
    }
    __syncthreads();
    if (tid < 32) {    // mean over queries of column tid
        float s = 0.f;
        for (int i = 0; i < 32; ++i) s += sm.attn.ps[i][tid];
        sm.attn.pbar[tid] = s * (1.f / 32.f);
    }
    __syncthreads();
    if (tid < 128) {   // attended mean[d] = sum_j pbar[j] * v[j][d]
        float s = 0.f;
        for (int j = 0; j < 32; ++j) s += sm.attn.pbar[j] * sm.attn.xs[j][tid];
        sm.attn.mvec[tid] = s;
    }
    __syncthreads();
    if (tid < 64) {    // mean
        float p = sm.attn.mvec[tid] + sm.attn.mvec[tid + 64];
        for (int off = 32; off; off >>= 1) p += __shfl_down(p, off);
        if (tid == 0) sm.attn.red[0] = p * (1.f / 128.f);
    }
    __syncthreads();
    float mu = sm.attn.red[0];
    if (tid < 64) {    // variance
        float t1 = sm.attn.mvec[tid] - mu, t2 = sm.attn.mvec[tid + 64] - mu;
        float p = t1 * t1 + t2 * t2;
        for (int off = 32; off; off >>= 1) p += __shfl_down(p, off);
        if (tid == 0) sm.attn.red[1] = rsqrtf(p * (1.f / 128.f) + 1e-5f);
    }
    __syncthreads();
    if (tid < 128) {
        yvec[tid] = (sm.attn.mvec[tid] - mu) * sm.attn.red[1] * ln_g[tid] + ln_b[tid];
    }
}

// ---------------------------------------------------------------------------
// Kernel 2: combo partials, v computed inline.
// grid = NCHUNK*4 blocks x 256 threads. blockIdx: chunk = bid>>2, coltile =
// bid&3 -> consecutive blocks stream contiguous rows of comboW.
// Wave access: 64 lanes x float4 = 1 KB contiguous (coalesced).
// seg<5 chunks: v from means. seg==5 chunks: inline proj (yvec . projW[:,m]).
// ---------------------------------------------------------------------------
__global__ __launch_bounds__(256) void combo_partial_kernel(
    const float* __restrict__ means,   // [5][4096]
    const float* __restrict__ ww,      // [6]
    const float* __restrict__ yvec,    // [128]
    const float* __restrict__ projW,   // [128][4096]
    const float* __restrict__ projb,   // [4096]
    const float* __restrict__ comboW,  // [24576][4096]
    float* __restrict__ part)          // [NCHUNK][4096]
{
    __shared__ float vsm[RPC];
    __shared__ float ys[128];
    const int tid = threadIdx.x;
    const int chunk = blockIdx.x >> 2;
    const int cb = blockIdx.x & 3;
    const int row0 = chunk * RPC;          // RPC divides 4096 -> chunk within one seg
    const int seg = row0 >> 12;

    float denom = 0.1f;
#pragma unroll
    for (int i = 0; i < 6; ++i) denom += ww[i];
    const float nw = (ww[seg] + 0.1f) / denom;

    if (seg < 5) {
        if (tid < RPC) vsm[tid] = means[seg * N_NEU + (row0 & 4095) + tid] * nw;
    } else {
        if (tid < 128) ys[tid] = yvec[tid];
        __syncthreads();
        if (tid < RPC) {
            int m = (row0 & 4095) + tid;
            float acc = projb[m];
            for (int e = 0; e < 128; ++e) acc += ys[e] * projW[e * N_NEU + m];
            vsm[tid] = acc * nw;
        }
    }
    __syncthreads();

    const int n4 = cb * 1024 + tid * 4;    // float col offset
    const float4* W4 = reinterpret_cast<const float4*>(comboW);
    size_t base = ((size_t)row0 * N_NEU + n4) >> 2;   // float4 index
    float4 acc = make_float4(0.f, 0.f, 0.f, 0.f);
#pragma unroll 4
    for (int r = 0; r < RPC; ++r) {
        float v = vsm[r];                              // LDS broadcast
        float4 w = W4[base + (size_t)r * 1024];        // coalesced 16 B/lane
        acc.x += v * w.x; acc.y += v * w.y; acc.z += v * w.z; acc.w += v * w.w;
    }
    reinterpret_cast<float4*>(part)[((size_t)chunk * N_NEU + n4) >> 2] = acc;
}

// ---------------------------------------------------------------------------
// Kernel 3: reduce partials + bias. 16 blocks x 256.
// ---------------------------------------------------------------------------
__global__ void combo_reduce_kernel(const float* __restrict__ part,
                                    const float* __restrict__ bias,
                                    float* __restrict__ out)
{
    int n = blockIdx.x * 256 + threadIdx.x;
    float acc = bias[n];
#pragma unroll 8
    for (int c = 0; c < NCHUNK; ++c) acc += part[(size_t)c * N_NEU + n];
    out[n] = acc;
}

// ---------------------------------------------------------------------------
extern "C" void kernel_launch(void* const* d_in, const int* in_sizes, int n_in,
                              void* d_out, int out_size, void* d_ws, size_t ws_size,
                              hipStream_t stream) {
    const float* inputEmbeds = (const float*)d_in[0];
    const float* neuronW     = (const float*)d_in[1];
    const float* neuronB     = (const float*)d_in[2];
    const float* Wq          = (const float*)d_in[3];
    const float* bq          = (const float*)d_in[4];
    const float* Wk          = (const float*)d_in[5];
    const float* bk          = (const float*)d_in[6];
    const float* Wv          = (const float*)d_in[7];
    const float* bv          = (const float*)d_in[8];
    const float* ln_g        = (const float*)d_in[9];
    const float* ln_b        = (const float*)d_in[10];
    const float* projW       = (const float*)d_in[11];
    const float* projb       = (const float*)d_in[12];
    const float* ww          = (const float*)d_in[13];
    const float* comboW      = (const float*)d_in[14];
    const float* combob      = (const float*)d_in[15];
    float* out = (float*)d_out;
    float* ws  = (float*)d_ws;

    float* means = ws;            // 5*4096 = 20480
    float* yvec  = ws + 20480;    // 128
    float* part  = ws + 20608;    // NCHUNK*4096

    means_attn_kernel<<<17, 256, 0, stream>>>(inputEmbeds, neuronW, neuronB,
                                              Wq, bq, Wk, bk, Wv, bv,
                                              ln_g, ln_b, means, yvec);
    combo_partial_kernel<<<NCHUNK * 4, 256, 0, stream>>>(means, ww, yvec,
                                                         projW, projb, comboW, part);
    combo_reduce_kernel<<<16, 256, 0, stream>>>(part, combob, out);
}